// Round 3
// baseline (483.054 us; speedup 1.0000x reference)
//
#include <hip/hip_runtime.h>
#include <stdint.h>

#define N_NODES 100000
#define N_EDGES 1600000
#define F 128
#define CBN 512                    // nodes per coarse bucket
#define NCBK 196                   // ceil(N_NODES/CBN)
#define CHUNK 4096                 // edges per binA/bhist block
#define BUFCAP 10240               // binB LDS edge buffer (mean 8192 + ~22 sigma)

typedef _Float16 f16;
typedef _Float16 f16x4 __attribute__((ext_vector_type(4)));
typedef _Float16 f16x8 __attribute__((ext_vector_type(8)));
typedef float f32x4 __attribute__((ext_vector_type(4)));

// edge pack: (src << 15) | (fp16 bits of w, sign bit dropped — w in [0,1))
__device__ inline float unpackw(unsigned int p) {
    unsigned short b = (unsigned short)(p & 0x7FFF);
    return (float)__builtin_bit_cast(f16, b);
}

// ---------------- front-end: 196-bucket histogram only ----------------

__global__ void k_zero0(int* bktcnt, unsigned int* edges) {
    int i = threadIdx.x;
    if (i < NCBK) bktcnt[i] = 0;
    // 8 zero sentinels past the edge array: src 0, w bits 0 -> w == +0.0
    if (i >= 248) edges[N_EDGES + (i - 248)] = 0u;
}

// LDS histogram of dst>>9 per 4096-edge chunk, one global atomic per (block,bucket)
__launch_bounds__(256)
__global__ void k_bhist(const int* __restrict__ ei, int* __restrict__ bktcnt, int e) {
    __shared__ int h[NCBK];
    int tid = threadIdx.x;
    if (tid < NCBK) h[tid] = 0;
    __syncthreads();
    int base = blockIdx.x * CHUNK;
    int cnt = min(CHUNK, e - base);
    const int* dst = ei + N_EDGES + base;
    if (cnt == CHUNK) {
        const int4* d4 = (const int4*)dst;
#pragma unroll
        for (int k = 0; k < 4; k++) {
            int4 v = d4[tid + k * 256];
            atomicAdd(&h[v.x >> 9], 1);
            atomicAdd(&h[v.y >> 9], 1);
            atomicAdd(&h[v.z >> 9], 1);
            atomicAdd(&h[v.w >> 9], 1);
        }
    } else {
        for (int i = tid; i < cnt; i += 256)
            atomicAdd(&h[dst[i] >> 9], 1);
    }
    __syncthreads();
    if (tid < NCBK && h[tid]) atomicAdd(&bktcnt[tid], h[tid]);
}

// one block: exclusive scan of 196 bucket counts -> gbase[197], init gcur, row[N]
__launch_bounds__(256)
__global__ void k_bktscan(const int* __restrict__ bktcnt, int* __restrict__ gbase,
                          int* __restrict__ gcur, int* __restrict__ row) {
    __shared__ int ls[256];
    int tid = threadIdx.x;
    int v = (tid < NCBK) ? bktcnt[tid] : 0;
    ls[tid] = v;
    __syncthreads();
    for (int off = 1; off < 256; off <<= 1) {
        int t = (tid >= off) ? ls[tid - off] : 0;
        __syncthreads();
        ls[tid] += t;
        __syncthreads();
    }
    int ex = ls[tid] - v;
    if (tid < NCBK) { gbase[tid] = ex; gcur[tid] = ex; }
    if (tid == NCBK) gbase[NCBK] = N_EDGES;
    if (tid == 0) row[N_NODES] = N_EDGES;
}

// ---------------- LDS write-combining binner (R13, proven) ----------------

__launch_bounds__(256)
__global__ void k_binA(const int* __restrict__ ei, const float* __restrict__ w,
                       int* __restrict__ gcur, int2* __restrict__ stage, int e) {
    __shared__ int hist[256];
    __shared__ int bst[257];
    __shared__ int gb[256];
    __shared__ int ls[256];
    __shared__ int rec[CHUNK];
    __shared__ int meta[CHUNK];
    int tid = threadIdx.x;
    int base = blockIdx.x * CHUNK;
    int cnt = min(CHUNK, e - base);
    hist[tid] = 0;
    __syncthreads();

    int ew_[16], mr_[16];
    int nloc = 0;
    if (cnt == CHUNK) {
#pragma unroll
        for (int k = 0; k < 16; k++) {
            int i = base + tid + k * 256;
            int s = ei[i];
            int d = ei[N_EDGES + i];
            f16 hw = (f16)w[i];
            unsigned short wb = __builtin_bit_cast(unsigned short, hw);
            ew_[k] = (int)(((unsigned int)s << 15) | (wb & 0x7FFF));
            int cb = d >> 9;
            int local = d & (CBN - 1);
            int r = atomicAdd(&hist[cb], 1);
            mr_[k] = (cb << 22) | (local << 13) | r;   // cb:8 local:9 r:13
        }
        nloc = 16;
    } else {
        for (int i = tid; i < cnt; i += 256) {
            int s = ei[base + i];
            int d = ei[N_EDGES + base + i];
            f16 hw = (f16)w[base + i];
            unsigned short wb = __builtin_bit_cast(unsigned short, hw);
            ew_[nloc] = (int)(((unsigned int)s << 15) | (wb & 0x7FFF));
            int cb = d >> 9;
            int local = d & (CBN - 1);
            int r = atomicAdd(&hist[cb], 1);
            mr_[nloc] = (cb << 22) | (local << 13) | r;
            nloc++;
        }
    }
    __syncthreads();
    int v = hist[tid];
    ls[tid] = v;
    __syncthreads();
    for (int off = 1; off < 256; off <<= 1) {
        int t = (tid >= off) ? ls[tid - off] : 0;
        __syncthreads();
        ls[tid] += t;
        __syncthreads();
    }
    bst[tid] = ls[tid] - v;
    if (tid == 255) bst[256] = ls[255];
    __syncthreads();
    for (int k = 0; k < nloc; k++) {
        int m = mr_[k];
        int cb = m >> 22;
        int pos = bst[cb] + (m & 0x1FFF);
        rec[pos] = ew_[k];
        meta[pos] = (cb << 9) | ((m >> 13) & 0x1FF);
    }
    __syncthreads();
    if (tid < NCBK) {
        int c = bst[tid + 1] - bst[tid];
        gb[tid] = c ? atomicAdd(&gcur[tid], c) : 0;
    }
    __syncthreads();
    for (int j = tid; j < cnt; j += 256) {
        int m = meta[j];
        int cb = m >> 9;
        stage[gb[cb] + (j - bst[cb])] = make_int2(m & 511, rec[j]);
    }
}

// binB: one block per coarse bucket. Derives per-node row[] itself:
// pass1 count locals -> LDS scan -> row write; pass2 permute to CSR in LDS;
// NEW (R17): per-node insertion sort by src before the final write. Packed word
// has src in bits 31:15, so sorting by u32 value == sorting by src. All agg
// walks then sweep src-space monotonically at ~equal rate -> the instantaneous
// L2 working set becomes a narrow moving band of H16 (sorted-stream locality).
__launch_bounds__(256)
__global__ void k_binB(const int2* __restrict__ stage, const int* __restrict__ gbase,
                       unsigned int* __restrict__ edges, int* __restrict__ row,
                       float* __restrict__ dinv) {
    __shared__ int cnt[CBN];
    __shared__ int ex[CBN + 1];
    __shared__ int cur[CBN];
    __shared__ int ls[256];
    __shared__ unsigned int buf[BUFCAP];
    int tid = threadIdx.x;
    int cb = blockIdx.x;
    int n0 = cb * CBN;
    int nn = min(CBN, N_NODES - n0);
    int base = gbase[cb];
    int hi = gbase[cb + 1];
    cnt[tid] = 0;
    cnt[tid + 256] = 0;
    __syncthreads();
    // pass 1: local histogram
    for (int j = base + tid; j < hi; j += 256)
        atomicAdd(&cnt[stage[j].x], 1);
    __syncthreads();
    // exclusive scan of 512 (2 per thread)
    int a = cnt[2 * tid], b = cnt[2 * tid + 1];
    int s = a + b;
    ls[tid] = s;
    __syncthreads();
    for (int off = 1; off < 256; off <<= 1) {
        int t = (tid >= off) ? ls[tid - off] : 0;
        __syncthreads();
        ls[tid] += t;
        __syncthreads();
    }
    int bx = ls[tid] - s;
    ex[2 * tid] = bx;
    ex[2 * tid + 1] = bx + a;
    cur[2 * tid] = bx;
    cur[2 * tid + 1] = bx + a;
    if (tid == 255) ex[512] = ls[255];
    __syncthreads();
    // row write (row[n0+nn] is the next block's base; row[N] by k_bktscan)
    for (int l = tid; l < nn; l += 256) row[n0 + l] = base + ex[l];
    // pass 2: permute to CSR order in LDS
    for (int j = base + tid; j < hi; j += 256) {
        int2 r = stage[j];
        int p = atomicAdd(&cur[r.x], 1);
        buf[p] = (unsigned int)r.y;
    }
    __syncthreads();
    // R17: per-node insertion sort by src (packed-word order == src order)
    for (int l = tid; l < nn; l += 256) {
        int lo = ex[l], h2 = ex[l + 1];
        for (int i = lo + 1; i < h2; i++) {
            unsigned int key = buf[i];
            int j = i - 1;
            while (j >= lo && buf[j] > key) { buf[j + 1] = buf[j]; j--; }
            buf[j + 1] = key;
        }
    }
    __syncthreads();
    int range = hi - base;
    for (int j = tid; j < range; j += 256)
        edges[base + j] = buf[j];
    // fused dinv: deg = 1 + sum w over the node's CSR slice (in LDS)
    for (int l = tid; l < nn; l += 256) {
        int lo = ex[l];
        int h2 = ex[l + 1];
        float sm = 1.0f;
        for (int j = lo; j < h2; j++) sm += unpackw(buf[j]);
        dinv[n0 + l] = rsqrtf(sm);
    }
}

// ---------------- fp32 -> fp16 conversions ----------------

__global__ void k_cvt(const float* __restrict__ X, f16* __restrict__ Y, int n8) {
    int i = blockIdx.x * blockDim.x + threadIdx.x;
    if (i < n8) {
        float4 a = ((const float4*)X)[i * 2];
        float4 b = ((const float4*)X)[i * 2 + 1];
        f16x8 o;
        o[0] = (f16)a.x; o[1] = (f16)a.y; o[2] = (f16)a.z; o[3] = (f16)a.w;
        o[4] = (f16)b.x; o[5] = (f16)b.y; o[6] = (f16)b.z; o[7] = (f16)b.w;
        ((f16x8*)Y)[i] = o;
    }
}

__global__ void k_wt2(const float* __restrict__ Wa, const float* __restrict__ Wb,
                      f16* __restrict__ Wta, f16* __restrict__ Wtb) {
    const float* W = blockIdx.x ? Wb : Wa;
    f16* Wt = blockIdx.x ? Wtb : Wta;
    int t = threadIdx.x;
#pragma unroll
    for (int it = 0; it < 64; it++) {
        int idx = t + it * 256;
        int k = idx >> 7, n = idx & 127;
        Wt[n * 128 + k] = (f16)W[idx];
    }
}

// ---------------- fp16 MFMA GEMM, epilogue scales rows by dinv ----------------

#define LDK 136

__launch_bounds__(256, 2)
__global__ void k_gemm16(const f16* __restrict__ A, const f16* __restrict__ Wt,
                         const float* __restrict__ dinv, f16* __restrict__ H, int nrows) {
    __shared__ f16 Ws[128 * LDK];
    int tid = threadIdx.x;
    int r0 = blockIdx.x * 128;
    int wave = tid >> 6;
    int lane = tid & 63;
    int lrow = lane & 15;
    int quad = lane >> 4;

    f16x8 a[2][4];
#pragma unroll
    for (int mt = 0; mt < 2; mt++) {
        int row = r0 + wave * 32 + mt * 16 + lrow;
#pragma unroll
        for (int kc = 0; kc < 4; kc++) {
            if (row < nrows)
                a[mt][kc] = *(const f16x8*)&A[(size_t)row * F + kc * 32 + quad * 8];
            else
                a[mt][kc] = (f16x8){};
        }
    }
#pragma unroll
    for (int it = 0; it < 8; it++) {
        int c = tid + it * 256;
        int rw = c >> 4;
        int off = (c & 15) * 8;
        *(f16x8*)&Ws[rw * LDK + off] = *(const f16x8*)&Wt[rw * 128 + off];
    }
    __syncthreads();

    f32x4 acc[2][8] = {};
#pragma unroll
    for (int kc = 0; kc < 4; kc++) {
        f16x8 b[8];
#pragma unroll
        for (int nt = 0; nt < 8; nt++)
            b[nt] = *(const f16x8*)&Ws[(nt * 16 + lrow) * LDK + kc * 32 + quad * 8];
#pragma unroll
        for (int nt = 0; nt < 8; nt++) {
            acc[0][nt] = __builtin_amdgcn_mfma_f32_16x16x32_f16(a[0][kc], b[nt], acc[0][nt], 0, 0, 0);
            acc[1][nt] = __builtin_amdgcn_mfma_f32_16x16x32_f16(a[1][kc], b[nt], acc[1][nt], 0, 0, 0);
        }
    }
    __syncthreads();
#pragma unroll
    for (int mt = 0; mt < 2; mt++) {
#pragma unroll
        for (int r = 0; r < 4; r++) {
            int lr = wave * 32 + mt * 16 + quad * 4 + r;
            int grow = r0 + lr;
            float dv = (grow < nrows) ? dinv[grow] : 0.f;
#pragma unroll
            for (int nt = 0; nt < 8; nt++)
                Ws[lr * 132 + nt * 16 + lrow] = (f16)(acc[mt][nt][r] * dv);
        }
    }
    __syncthreads();
#pragma unroll
    for (int it = 0; it < 8; it++) {
        int c = it * 256 + tid;
        int rw = c >> 4;
        int col = (c & 15) * 8;
        int grow = r0 + rw;
        if (grow < nrows)
            *(f16x8*)&H[(size_t)grow * F + col] = *(const f16x8*)&Ws[rw * 132 + col];
    }
}

// ---------------- aggregation (R16 structure): 8-deep unroll + uint4 edge loads ----------------

__launch_bounds__(256)
__global__ void k_agg(const f16* __restrict__ H16, const int* __restrict__ row,
                      const unsigned int* __restrict__ edges,
                      const float* __restrict__ dinv, const float* __restrict__ bias,
                      f16* __restrict__ out, int n) {
    int node = blockIdx.x * 16 + (threadIdx.x >> 4);
    if (node >= n) return;
    int sub = threadIdx.x & 15;
    int beg = row[node], end = row[node + 1];
    float acc0[8] = {}, acc1[8] = {}, acc2[8] = {}, acc3[8] = {};
    for (int t = (beg & ~3); t < end; t += 8) {
        uint4 ea = *(const uint4*)&edges[t];
        uint4 eb = *(const uint4*)&edges[t + 4];
        unsigned int e[8] = {ea.x, ea.y, ea.z, ea.w, eb.x, eb.y, eb.z, eb.w};
        float w[8];
        unsigned int srcw[8];
#pragma unroll
        for (int k = 0; k < 8; k++) {
            bool live = (t + k >= beg) && (t + k < end);
            w[k] = live ? unpackw(e[k]) : 0.f;
            srcw[k] = (t + k < end) ? e[k] : ea.x;
        }
        f16x8 v[8];
#pragma unroll
        for (int k = 0; k < 8; k++)
            v[k] = *(const f16x8*)&H16[(size_t)(srcw[k] >> 15) * F + sub * 8];
#pragma unroll
        for (int j = 0; j < 8; j++) {
            acc0[j] = fmaf(w[0], (float)v[0][j], acc0[j]);
            acc1[j] = fmaf(w[1], (float)v[1][j], acc1[j]);
            acc2[j] = fmaf(w[2], (float)v[2][j], acc2[j]);
            acc3[j] = fmaf(w[3], (float)v[3][j], acc3[j]);
            acc0[j] = fmaf(w[4], (float)v[4][j], acc0[j]);
            acc1[j] = fmaf(w[5], (float)v[5][j], acc1[j]);
            acc2[j] = fmaf(w[6], (float)v[6][j], acc2[j]);
            acc3[j] = fmaf(w[7], (float)v[7][j], acc3[j]);
        }
    }
    float dd = dinv[node];
    f16x8 h = *(const f16x8*)&H16[(size_t)node * F + sub * 8];
    float4 b0 = *(const float4*)&bias[sub * 8];
    float4 b1 = *(const float4*)&bias[sub * 8 + 4];
    float bb[8] = {b0.x, b0.y, b0.z, b0.w, b1.x, b1.y, b1.z, b1.w};
    f16x8 o;
#pragma unroll
    for (int j = 0; j < 8; j++) {
        float a = acc0[j] + acc1[j] + acc2[j] + acc3[j] + (float)h[j];
        o[j] = (f16)fmaxf(fmaf(dd, a, bb[j]), 0.f);
    }
    *(f16x8*)&out[(size_t)node * F + sub * 8] = o;
}

// agg3 fused with final dot: s'[node] = dinv[node] * ( relu(agg3) . Wfin )
__launch_bounds__(256)
__global__ void k_agg_dot(const f16* __restrict__ H16, const int* __restrict__ row,
                          const unsigned int* __restrict__ edges,
                          const float* __restrict__ dinv, const float* __restrict__ bias,
                          const float* __restrict__ Wf, float* __restrict__ sout, int n) {
    int node = blockIdx.x * 16 + (threadIdx.x >> 4);
    if (node >= n) return;
    int sub = threadIdx.x & 15;
    int beg = row[node], end = row[node + 1];
    float acc0[8] = {}, acc1[8] = {}, acc2[8] = {}, acc3[8] = {};
    for (int t = (beg & ~3); t < end; t += 8) {
        uint4 ea = *(const uint4*)&edges[t];
        uint4 eb = *(const uint4*)&edges[t + 4];
        unsigned int e[8] = {ea.x, ea.y, ea.z, ea.w, eb.x, eb.y, eb.z, eb.w};
        float w[8];
        unsigned int srcw[8];
#pragma unroll
        for (int k = 0; k < 8; k++) {
            bool live = (t + k >= beg) && (t + k < end);
            w[k] = live ? unpackw(e[k]) : 0.f;
            srcw[k] = (t + k < end) ? e[k] : ea.x;
        }
        f16x8 v[8];
#pragma unroll
        for (int k = 0; k < 8; k++)
            v[k] = *(const f16x8*)&H16[(size_t)(srcw[k] >> 15) * F + sub * 8];
#pragma unroll
        for (int j = 0; j < 8; j++) {
            acc0[j] = fmaf(w[0], (float)v[0][j], acc0[j]);
            acc1[j] = fmaf(w[1], (float)v[1][j], acc1[j]);
            acc2[j] = fmaf(w[2], (float)v[2][j], acc2[j]);
            acc3[j] = fmaf(w[3], (float)v[3][j], acc3[j]);
            acc0[j] = fmaf(w[4], (float)v[4][j], acc0[j]);
            acc1[j] = fmaf(w[5], (float)v[5][j], acc1[j]);
            acc2[j] = fmaf(w[6], (float)v[6][j], acc2[j]);
            acc3[j] = fmaf(w[7], (float)v[7][j], acc3[j]);
        }
    }
    float dd = dinv[node];
    f16x8 h = *(const f16x8*)&H16[(size_t)node * F + sub * 8];
    float4 b0 = *(const float4*)&bias[sub * 8];
    float4 b1 = *(const float4*)&bias[sub * 8 + 4];
    float bb[8] = {b0.x, b0.y, b0.z, b0.w, b1.x, b1.y, b1.z, b1.w};
    float4 w0v = *(const float4*)&Wf[sub * 8];
    float4 w1v = *(const float4*)&Wf[sub * 8 + 4];
    float ww[8] = {w0v.x, w0v.y, w0v.z, w0v.w, w1v.x, w1v.y, w1v.z, w1v.w};
    float p = 0.f;
#pragma unroll
    for (int j = 0; j < 8; j++) {
        float a = acc0[j] + acc1[j] + acc2[j] + acc3[j] + (float)h[j];
        p += fmaxf(fmaf(dd, a, bb[j]), 0.f) * ww[j];
    }
    p += __shfl_xor(p, 8, 64);
    p += __shfl_xor(p, 4, 64);
    p += __shfl_xor(p, 2, 64);
    p += __shfl_xor(p, 1, 64);
    if (sub == 0) sout[node] = dd * p;
}

__global__ void k_aggs(const float* __restrict__ s, const int* __restrict__ row,
                       const unsigned int* __restrict__ edges,
                       const float* __restrict__ dinv, const float* __restrict__ bf,
                       float* __restrict__ out, int n) {
    int i = blockIdx.x * blockDim.x + threadIdx.x;
    if (i >= n) return;
    float dd = dinv[i];
    float ae = s[i];
    int beg = row[i], end = row[i + 1];
    for (int j = beg; j < end; j++) {
        unsigned int p = edges[j];
        ae = fmaf(unpackw(p), s[p >> 15], ae);
    }
    out[i] = fmaf(dd, ae, bf[0]);
}

// ---------------- host launch ----------------

extern "C" void kernel_launch(void* const* d_in, const int* in_sizes, int n_in,
                              void* d_out, int out_size, void* d_ws, size_t ws_size,
                              hipStream_t stream) {
    const float* x    = (const float*)d_in[0];
    const int*   ei   = (const int*)d_in[1];
    const float* ew   = (const float*)d_in[2];
    const float* Win  = (const float*)d_in[3];
    const float* bin  = (const float*)d_in[4];
    const float* Wmid = (const float*)d_in[5];
    const float* bmid = (const float*)d_in[6];
    const float* Wfin = (const float*)d_in[7];
    const float* bfin = (const float*)d_in[8];
    float* out = (float*)d_out;

    char* ws = (char*)d_ws;
    size_t off = 0;
    auto alloc = [&](size_t bytes) -> char* {
        char* p = ws + off;
        off = (off + bytes + 255) & ~(size_t)255;
        return p;
    };
    float* dinv  = (float*)alloc((size_t)N_NODES * 4);
    int*   row   = (int*)alloc((size_t)(N_NODES + 1) * 4);
    unsigned int* edges = (unsigned int*)alloc((size_t)(N_EDGES + 8) * 4);  // +8 sentinels
    int*   bktcnt = (int*)alloc(256 * 4);
    int*   gbase  = (int*)alloc(256 * 4);
    int*   gcur   = (int*)alloc(256 * 4);
    f16*   wtin  = (f16*)alloc(128 * 128 * 2);
    f16*   wtmid = (f16*)alloc(128 * 128 * 2);
    f16*   H16   = (f16*)alloc((size_t)N_NODES * F * 2);   // gemm out (dinv-scaled) / agg in
    f16*   AB16  = (f16*)alloc((size_t)N_NODES * F * 2);   // x16 -> agg out chain
    // stage aliased into H16 (consumed by binB before gemm1 writes H16):
    int2* stage = (int2*)H16;                               // 12.8 MB
    float* sbuf = (float*)AB16;  // aliased: consumed by gemm3 before agg_dot writes

    dim3 b256(256);
    int gN = (N_NODES + 255) / 256;
    int gW = (N_NODES + 15) / 16;
    int gG = (N_NODES + 127) / 128;
    int n8 = N_NODES * F / 8;
    int gC = (n8 + 255) / 256;
    int gA = (N_EDGES + CHUNK - 1) / CHUNK;   // 391

    hipLaunchKernelGGL(k_zero0, dim3(1), b256, 0, stream, bktcnt, edges);
    hipLaunchKernelGGL(k_bhist, dim3(gA), b256, 0, stream, ei, bktcnt, N_EDGES);
    hipLaunchKernelGGL(k_bktscan, dim3(1), b256, 0, stream, bktcnt, gbase, gcur, row);
    hipLaunchKernelGGL(k_binA, dim3(gA), b256, 0, stream, ei, ew, gcur, stage, N_EDGES);
    hipLaunchKernelGGL(k_binB, dim3(NCBK), b256, 0, stream, stage, gbase, edges, row, dinv);
    hipLaunchKernelGGL(k_cvt, dim3(gC), b256, 0, stream, x, AB16, n8);
    hipLaunchKernelGGL(k_wt2, dim3(2), b256, 0, stream, Win, Wmid, wtin, wtmid);

    hipLaunchKernelGGL(k_gemm16, dim3(gG), b256, 0, stream, AB16, wtin, dinv, H16, N_NODES);
    hipLaunchKernelGGL(k_agg, dim3(gW), b256, 0, stream, H16, row, edges, dinv, bin, AB16, N_NODES);
    hipLaunchKernelGGL(k_gemm16, dim3(gG), b256, 0, stream, AB16, wtmid, dinv, H16, N_NODES);
    hipLaunchKernelGGL(k_agg, dim3(gW), b256, 0, stream, H16, row, edges, dinv, bmid, AB16, N_NODES);
    hipLaunchKernelGGL(k_gemm16, dim3(gG), b256, 0, stream, AB16, wtmid, dinv, H16, N_NODES);
    hipLaunchKernelGGL(k_agg_dot, dim3(gW), b256, 0, stream, H16, row, edges, dinv, bmid, Wfin, sbuf, N_NODES);
    hipLaunchKernelGGL(k_aggs, dim3(gN), b256, 0, stream, sbuf, row, edges, dinv, bfin, out, N_NODES);
}

// Round 4
// 387.449 us; speedup vs baseline: 1.2468x; 1.2468x over previous
//
#include <hip/hip_runtime.h>
#include <stdint.h>

#define N_NODES 100000
#define N_EDGES 1600000
#define F 128
#define CBN 512                    // nodes per coarse bucket
#define NCBK 196                   // ceil(N_NODES/CBN)
#define CHUNK 4096                 // edges per binA block
#define BUFCAP 10240               // per-bucket region cap (mean 8163 + ~23 sigma)

typedef _Float16 f16;
typedef _Float16 f16x4 __attribute__((ext_vector_type(4)));
typedef _Float16 f16x8 __attribute__((ext_vector_type(8)));
typedef float f32x4 __attribute__((ext_vector_type(4)));

// edge pack: (src << 15) | (fp16 bits of w, sign bit dropped — w in [0,1))
__device__ inline float unpackw(unsigned int p) {
    unsigned short b = (unsigned short)(p & 0x7FFF);
    return (float)__builtin_bit_cast(f16, b);
}

// ---------------- R18 front-end: padded-bucket, no histogram/scan ----------------
// Each bucket cb owns stage[cb*BUFCAP ..] and edges[cb*BUFCAP ..]; binA appends
// via gcur (zero-based), binB compacts within the bucket. CSR is per-node
// (beg,end) pairs (row2) so the inter-bucket padding gaps are harmless.
// Deleted vs R16: k_bhist (2 passes over dst), k_bktscan.

__global__ void k_zero0(int* gcur, unsigned int* edges) {
    int i = threadIdx.x;
    if (i < NCBK) gcur[i] = 0;
    // 8 zero sentinels past the last bucket region (uint4 tail overread)
    if (i >= 248) edges[(size_t)NCBK * BUFCAP + (i - 248)] = 0u;
}

// ---------------- LDS write-combining binner (R13, proven) ----------------
// Measured R9-R12: scattered/temporally-sparse partial-line writes cost ~5x
// write amplification. binA converts per-edge scatter into per-(block,bin)
// contiguous runs claimed with one atomic each.

__launch_bounds__(256)
__global__ void k_binA(const int* __restrict__ ei, const float* __restrict__ w,
                       int* __restrict__ gcur, int2* __restrict__ stage, int e) {
    __shared__ int hist[256];
    __shared__ int bst[257];
    __shared__ int gb[256];
    __shared__ int ls[256];
    __shared__ int rec[CHUNK];
    __shared__ int meta[CHUNK];
    int tid = threadIdx.x;
    int base = blockIdx.x * CHUNK;
    int cnt = min(CHUNK, e - base);
    hist[tid] = 0;
    __syncthreads();

    int ew_[16], mr_[16];
    int nloc = 0;
    if (cnt == CHUNK) {
#pragma unroll
        for (int k = 0; k < 16; k++) {
            int i = base + tid + k * 256;
            int s = ei[i];
            int d = ei[N_EDGES + i];
            f16 hw = (f16)w[i];
            unsigned short wb = __builtin_bit_cast(unsigned short, hw);
            ew_[k] = (int)(((unsigned int)s << 15) | (wb & 0x7FFF));
            int cb = d >> 9;
            int local = d & (CBN - 1);
            int r = atomicAdd(&hist[cb], 1);
            mr_[k] = (cb << 22) | (local << 13) | r;   // cb:8 local:9 r:13
        }
        nloc = 16;
    } else {
        for (int i = tid; i < cnt; i += 256) {
            int s = ei[base + i];
            int d = ei[N_EDGES + base + i];
            f16 hw = (f16)w[base + i];
            unsigned short wb = __builtin_bit_cast(unsigned short, hw);
            ew_[nloc] = (int)(((unsigned int)s << 15) | (wb & 0x7FFF));
            int cb = d >> 9;
            int local = d & (CBN - 1);
            int r = atomicAdd(&hist[cb], 1);
            mr_[nloc] = (cb << 22) | (local << 13) | r;
            nloc++;
        }
    }
    __syncthreads();
    int v = hist[tid];
    ls[tid] = v;
    __syncthreads();
    for (int off = 1; off < 256; off <<= 1) {
        int t = (tid >= off) ? ls[tid - off] : 0;
        __syncthreads();
        ls[tid] += t;
        __syncthreads();
    }
    bst[tid] = ls[tid] - v;
    if (tid == 255) bst[256] = ls[255];
    __syncthreads();
    for (int k = 0; k < nloc; k++) {
        int m = mr_[k];
        int cb = m >> 22;
        int pos = bst[cb] + (m & 0x1FFF);
        rec[pos] = ew_[k];
        meta[pos] = (cb << 9) | ((m >> 13) & 0x1FF);
    }
    __syncthreads();
    if (tid < NCBK) {
        int c = bst[tid + 1] - bst[tid];
        gb[tid] = c ? atomicAdd(&gcur[tid], c) : 0;
    }
    __syncthreads();
    for (int j = tid; j < cnt; j += 256) {
        int m = meta[j];
        int cb = m >> 9;
        stage[(size_t)cb * BUFCAP + gb[cb] + (j - bst[cb])] = make_int2(m & 511, rec[j]);
    }
}

// binB: one block per coarse bucket. pass1 count locals -> LDS scan -> row2
// write; pass2 permute to CSR order in LDS; coalesced final write + fused dinv.
__launch_bounds__(256)
__global__ void k_binB(const int2* __restrict__ stage, const int* __restrict__ gcur,
                       unsigned int* __restrict__ edges, int2* __restrict__ row2,
                       float* __restrict__ dinv) {
    __shared__ int cnt[CBN];
    __shared__ int ex[CBN + 1];
    __shared__ int cur[CBN];
    __shared__ int ls[256];
    __shared__ unsigned int buf[BUFCAP];
    int tid = threadIdx.x;
    int cb = blockIdx.x;
    int n0 = cb * CBN;
    int nn = min(CBN, N_NODES - n0);
    size_t sbase = (size_t)cb * BUFCAP;
    int ecnt = gcur[cb];
    cnt[tid] = 0;
    cnt[tid + 256] = 0;
    __syncthreads();
    // pass 1: local histogram
    for (int j = tid; j < ecnt; j += 256)
        atomicAdd(&cnt[stage[sbase + j].x], 1);
    __syncthreads();
    // exclusive scan of 512 (2 per thread)
    int a = cnt[2 * tid], b = cnt[2 * tid + 1];
    int s = a + b;
    ls[tid] = s;
    __syncthreads();
    for (int off = 1; off < 256; off <<= 1) {
        int t = (tid >= off) ? ls[tid - off] : 0;
        __syncthreads();
        ls[tid] += t;
        __syncthreads();
    }
    int bx = ls[tid] - s;
    ex[2 * tid] = bx;
    ex[2 * tid + 1] = bx + a;
    cur[2 * tid] = bx;
    cur[2 * tid + 1] = bx + a;
    if (tid == 255) ex[512] = ls[255];
    __syncthreads();
    // per-node (beg,end) pairs — padding gaps between buckets are harmless
    for (int l = tid; l < nn; l += 256)
        row2[n0 + l] = make_int2((int)sbase + ex[l], (int)sbase + ex[l + 1]);
    // pass 2: permute to CSR order in LDS
    for (int j = tid; j < ecnt; j += 256) {
        int2 r = stage[sbase + j];
        int p = atomicAdd(&cur[r.x], 1);
        buf[p] = (unsigned int)r.y;
    }
    __syncthreads();
    for (int j = tid; j < ecnt; j += 256)
        edges[sbase + j] = buf[j];
    // fused dinv: deg = 1 + sum w over the node's CSR slice (in LDS)
    for (int l = tid; l < nn; l += 256) {
        int lo = ex[l];
        int h2 = ex[l + 1];
        float sm = 1.0f;
        for (int j = lo; j < h2; j++) sm += unpackw(buf[j]);
        dinv[n0 + l] = rsqrtf(sm);
    }
}

// ---------------- weight transpose ----------------

__global__ void k_wt2(const float* __restrict__ Wa, const float* __restrict__ Wb,
                      f16* __restrict__ Wta, f16* __restrict__ Wtb) {
    const float* W = blockIdx.x ? Wb : Wa;
    f16* Wt = blockIdx.x ? Wtb : Wta;
    int t = threadIdx.x;
#pragma unroll
    for (int it = 0; it < 64; it++) {
        int idx = t + it * 256;
        int k = idx >> 7, n = idx & 127;
        Wt[n * 128 + k] = (f16)W[idx];
    }
}

// ---------------- fp16 MFMA GEMM, epilogue scales rows by dinv ----------------

#define LDK 136

__launch_bounds__(256, 2)
__global__ void k_gemm16(const f16* __restrict__ A, const f16* __restrict__ Wt,
                         const float* __restrict__ dinv, f16* __restrict__ H, int nrows) {
    __shared__ f16 Ws[128 * LDK];
    int tid = threadIdx.x;
    int r0 = blockIdx.x * 128;
    int wave = tid >> 6;
    int lane = tid & 63;
    int lrow = lane & 15;
    int quad = lane >> 4;

    f16x8 a[2][4];
#pragma unroll
    for (int mt = 0; mt < 2; mt++) {
        int row = r0 + wave * 32 + mt * 16 + lrow;
#pragma unroll
        for (int kc = 0; kc < 4; kc++) {
            if (row < nrows)
                a[mt][kc] = *(const f16x8*)&A[(size_t)row * F + kc * 32 + quad * 8];
            else
                a[mt][kc] = (f16x8){};
        }
    }
#pragma unroll
    for (int it = 0; it < 8; it++) {
        int c = tid + it * 256;
        int rw = c >> 4;
        int off = (c & 15) * 8;
        *(f16x8*)&Ws[rw * LDK + off] = *(const f16x8*)&Wt[rw * 128 + off];
    }
    __syncthreads();

    f32x4 acc[2][8] = {};
#pragma unroll
    for (int kc = 0; kc < 4; kc++) {
        f16x8 b[8];
#pragma unroll
        for (int nt = 0; nt < 8; nt++)
            b[nt] = *(const f16x8*)&Ws[(nt * 16 + lrow) * LDK + kc * 32 + quad * 8];
#pragma unroll
        for (int nt = 0; nt < 8; nt++) {
            acc[0][nt] = __builtin_amdgcn_mfma_f32_16x16x32_f16(a[0][kc], b[nt], acc[0][nt], 0, 0, 0);
            acc[1][nt] = __builtin_amdgcn_mfma_f32_16x16x32_f16(a[1][kc], b[nt], acc[1][nt], 0, 0, 0);
        }
    }
    __syncthreads();
#pragma unroll
    for (int mt = 0; mt < 2; mt++) {
#pragma unroll
        for (int r = 0; r < 4; r++) {
            int lr = wave * 32 + mt * 16 + quad * 4 + r;
            int grow = r0 + lr;
            float dv = (grow < nrows) ? dinv[grow] : 0.f;
#pragma unroll
            for (int nt = 0; nt < 8; nt++)
                Ws[lr * 132 + nt * 16 + lrow] = (f16)(acc[mt][nt][r] * dv);
        }
    }
    __syncthreads();
#pragma unroll
    for (int it = 0; it < 8; it++) {
        int c = it * 256 + tid;
        int rw = c >> 4;
        int col = (c & 15) * 8;
        int grow = r0 + rw;
        if (grow < nrows)
            *(f16x8*)&H[(size_t)grow * F + col] = *(const f16x8*)&Ws[rw * 132 + col];
    }
}

// gemm1 with fused fp32->fp16 A conversion (kills the k_cvt pass)
__launch_bounds__(256, 2)
__global__ void k_gemmf(const float* __restrict__ A, const f16* __restrict__ Wt,
                        const float* __restrict__ dinv, f16* __restrict__ H, int nrows) {
    __shared__ f16 Ws[128 * LDK];
    int tid = threadIdx.x;
    int r0 = blockIdx.x * 128;
    int wave = tid >> 6;
    int lane = tid & 63;
    int lrow = lane & 15;
    int quad = lane >> 4;

    f16x8 a[2][4];
#pragma unroll
    for (int mt = 0; mt < 2; mt++) {
        int row = r0 + wave * 32 + mt * 16 + lrow;
#pragma unroll
        for (int kc = 0; kc < 4; kc++) {
            if (row < nrows) {
                float4 lo = *(const float4*)&A[(size_t)row * F + kc * 32 + quad * 8];
                float4 hi = *(const float4*)&A[(size_t)row * F + kc * 32 + quad * 8 + 4];
                f16x8 f;
                f[0] = (f16)lo.x; f[1] = (f16)lo.y; f[2] = (f16)lo.z; f[3] = (f16)lo.w;
                f[4] = (f16)hi.x; f[5] = (f16)hi.y; f[6] = (f16)hi.z; f[7] = (f16)hi.w;
                a[mt][kc] = f;
            } else {
                a[mt][kc] = (f16x8){};
            }
        }
    }
#pragma unroll
    for (int it = 0; it < 8; it++) {
        int c = tid + it * 256;
        int rw = c >> 4;
        int off = (c & 15) * 8;
        *(f16x8*)&Ws[rw * LDK + off] = *(const f16x8*)&Wt[rw * 128 + off];
    }
    __syncthreads();

    f32x4 acc[2][8] = {};
#pragma unroll
    for (int kc = 0; kc < 4; kc++) {
        f16x8 b[8];
#pragma unroll
        for (int nt = 0; nt < 8; nt++)
            b[nt] = *(const f16x8*)&Ws[(nt * 16 + lrow) * LDK + kc * 32 + quad * 8];
#pragma unroll
        for (int nt = 0; nt < 8; nt++) {
            acc[0][nt] = __builtin_amdgcn_mfma_f32_16x16x32_f16(a[0][kc], b[nt], acc[0][nt], 0, 0, 0);
            acc[1][nt] = __builtin_amdgcn_mfma_f32_16x16x32_f16(a[1][kc], b[nt], acc[1][nt], 0, 0, 0);
        }
    }
    __syncthreads();
#pragma unroll
    for (int mt = 0; mt < 2; mt++) {
#pragma unroll
        for (int r = 0; r < 4; r++) {
            int lr = wave * 32 + mt * 16 + quad * 4 + r;
            int grow = r0 + lr;
            float dv = (grow < nrows) ? dinv[grow] : 0.f;
#pragma unroll
            for (int nt = 0; nt < 8; nt++)
                Ws[lr * 132 + nt * 16 + lrow] = (f16)(acc[mt][nt][r] * dv);
        }
    }
    __syncthreads();
#pragma unroll
    for (int it = 0; it < 8; it++) {
        int c = it * 256 + tid;
        int rw = c >> 4;
        int col = (c & 15) * 8;
        int grow = r0 + rw;
        if (grow < nrows)
            *(f16x8*)&H[(size_t)grow * F + col] = *(const f16x8*)&Ws[rw * 132 + col];
    }
}

// ---------------- aggregation (R16 structure, row2 CSR) ----------------

__launch_bounds__(256)
__global__ void k_agg(const f16* __restrict__ H16, const int2* __restrict__ row2,
                      const unsigned int* __restrict__ edges,
                      const float* __restrict__ dinv, const float* __restrict__ bias,
                      f16* __restrict__ out, int n) {
    int node = blockIdx.x * 16 + (threadIdx.x >> 4);
    if (node >= n) return;
    int sub = threadIdx.x & 15;
    int2 rr = row2[node];
    int beg = rr.x, end = rr.y;
    float acc0[8] = {}, acc1[8] = {}, acc2[8] = {}, acc3[8] = {};
    for (int t = (beg & ~3); t < end; t += 8) {
        uint4 ea = *(const uint4*)&edges[t];
        uint4 eb = *(const uint4*)&edges[t + 4];
        unsigned int e[8] = {ea.x, ea.y, ea.z, ea.w, eb.x, eb.y, eb.z, eb.w};
        float w[8];
        unsigned int srcw[8];
#pragma unroll
        for (int k = 0; k < 8; k++) {
            bool live = (t + k >= beg) && (t + k < end);
            w[k] = live ? unpackw(e[k]) : 0.f;
            srcw[k] = (t + k < end) ? e[k] : ea.x;
        }
        f16x8 v[8];
#pragma unroll
        for (int k = 0; k < 8; k++)
            v[k] = *(const f16x8*)&H16[(size_t)(srcw[k] >> 15) * F + sub * 8];
#pragma unroll
        for (int j = 0; j < 8; j++) {
            acc0[j] = fmaf(w[0], (float)v[0][j], acc0[j]);
            acc1[j] = fmaf(w[1], (float)v[1][j], acc1[j]);
            acc2[j] = fmaf(w[2], (float)v[2][j], acc2[j]);
            acc3[j] = fmaf(w[3], (float)v[3][j], acc3[j]);
            acc0[j] = fmaf(w[4], (float)v[4][j], acc0[j]);
            acc1[j] = fmaf(w[5], (float)v[5][j], acc1[j]);
            acc2[j] = fmaf(w[6], (float)v[6][j], acc2[j]);
            acc3[j] = fmaf(w[7], (float)v[7][j], acc3[j]);
        }
    }
    float dd = dinv[node];
    f16x8 h = *(const f16x8*)&H16[(size_t)node * F + sub * 8];
    float4 b0 = *(const float4*)&bias[sub * 8];
    float4 b1 = *(const float4*)&bias[sub * 8 + 4];
    float bb[8] = {b0.x, b0.y, b0.z, b0.w, b1.x, b1.y, b1.z, b1.w};
    f16x8 o;
#pragma unroll
    for (int j = 0; j < 8; j++) {
        float a = acc0[j] + acc1[j] + acc2[j] + acc3[j] + (float)h[j];
        o[j] = (f16)fmaxf(fmaf(dd, a, bb[j]), 0.f);
    }
    *(f16x8*)&out[(size_t)node * F + sub * 8] = o;
}

// agg3 fused with final dot: s'[node] = dinv[node] * ( relu(agg3) . Wfin )
__launch_bounds__(256)
__global__ void k_agg_dot(const f16* __restrict__ H16, const int2* __restrict__ row2,
                          const unsigned int* __restrict__ edges,
                          const float* __restrict__ dinv, const float* __restrict__ bias,
                          const float* __restrict__ Wf, float* __restrict__ sout, int n) {
    int node = blockIdx.x * 16 + (threadIdx.x >> 4);
    if (node >= n) return;
    int sub = threadIdx.x & 15;
    int2 rr = row2[node];
    int beg = rr.x, end = rr.y;
    float acc0[8] = {}, acc1[8] = {}, acc2[8] = {}, acc3[8] = {};
    for (int t = (beg & ~3); t < end; t += 8) {
        uint4 ea = *(const uint4*)&edges[t];
        uint4 eb = *(const uint4*)&edges[t + 4];
        unsigned int e[8] = {ea.x, ea.y, ea.z, ea.w, eb.x, eb.y, eb.z, eb.w};
        float w[8];
        unsigned int srcw[8];
#pragma unroll
        for (int k = 0; k < 8; k++) {
            bool live = (t + k >= beg) && (t + k < end);
            w[k] = live ? unpackw(e[k]) : 0.f;
            srcw[k] = (t + k < end) ? e[k] : ea.x;
        }
        f16x8 v[8];
#pragma unroll
        for (int k = 0; k < 8; k++)
            v[k] = *(const f16x8*)&H16[(size_t)(srcw[k] >> 15) * F + sub * 8];
#pragma unroll
        for (int j = 0; j < 8; j++) {
            acc0[j] = fmaf(w[0], (float)v[0][j], acc0[j]);
            acc1[j] = fmaf(w[1], (float)v[1][j], acc1[j]);
            acc2[j] = fmaf(w[2], (float)v[2][j], acc2[j]);
            acc3[j] = fmaf(w[3], (float)v[3][j], acc3[j]);
            acc0[j] = fmaf(w[4], (float)v[4][j], acc0[j]);
            acc1[j] = fmaf(w[5], (float)v[5][j], acc1[j]);
            acc2[j] = fmaf(w[6], (float)v[6][j], acc2[j]);
            acc3[j] = fmaf(w[7], (float)v[7][j], acc3[j]);
        }
    }
    float dd = dinv[node];
    f16x8 h = *(const f16x8*)&H16[(size_t)node * F + sub * 8];
    float4 b0 = *(const float4*)&bias[sub * 8];
    float4 b1 = *(const float4*)&bias[sub * 8 + 4];
    float bb[8] = {b0.x, b0.y, b0.z, b0.w, b1.x, b1.y, b1.z, b1.w};
    float4 w0v = *(const float4*)&Wf[sub * 8];
    float4 w1v = *(const float4*)&Wf[sub * 8 + 4];
    float ww[8] = {w0v.x, w0v.y, w0v.z, w0v.w, w1v.x, w1v.y, w1v.z, w1v.w};
    float p = 0.f;
#pragma unroll
    for (int j = 0; j < 8; j++) {
        float a = acc0[j] + acc1[j] + acc2[j] + acc3[j] + (float)h[j];
        p += fmaxf(fmaf(dd, a, bb[j]), 0.f) * ww[j];
    }
    p += __shfl_xor(p, 8, 64);
    p += __shfl_xor(p, 4, 64);
    p += __shfl_xor(p, 2, 64);
    p += __shfl_xor(p, 1, 64);
    if (sub == 0) sout[node] = dd * p;
}

__global__ void k_aggs(const float* __restrict__ s, const int2* __restrict__ row2,
                       const unsigned int* __restrict__ edges,
                       const float* __restrict__ dinv, const float* __restrict__ bf,
                       float* __restrict__ out, int n) {
    int i = blockIdx.x * blockDim.x + threadIdx.x;
    if (i >= n) return;
    float dd = dinv[i];
    float ae = s[i];
    int2 rr = row2[i];
    for (int j = rr.x; j < rr.y; j++) {
        unsigned int p = edges[j];
        ae = fmaf(unpackw(p), s[p >> 15], ae);
    }
    out[i] = fmaf(dd, ae, bf[0]);
}

// ---------------- host launch ----------------

extern "C" void kernel_launch(void* const* d_in, const int* in_sizes, int n_in,
                              void* d_out, int out_size, void* d_ws, size_t ws_size,
                              hipStream_t stream) {
    const float* x    = (const float*)d_in[0];
    const int*   ei   = (const int*)d_in[1];
    const float* ew   = (const float*)d_in[2];
    const float* Win  = (const float*)d_in[3];
    const float* bin  = (const float*)d_in[4];
    const float* Wmid = (const float*)d_in[5];
    const float* bmid = (const float*)d_in[6];
    const float* Wfin = (const float*)d_in[7];
    const float* bfin = (const float*)d_in[8];
    float* out = (float*)d_out;

    char* ws = (char*)d_ws;
    size_t off = 0;
    auto alloc = [&](size_t bytes) -> char* {
        char* p = ws + off;
        off = (off + bytes + 255) & ~(size_t)255;
        return p;
    };
    float* dinv  = (float*)alloc((size_t)N_NODES * 4);
    int2*  row2  = (int2*)alloc((size_t)N_NODES * 8);
    unsigned int* edges = (unsigned int*)alloc(((size_t)NCBK * BUFCAP + 8) * 4);  // padded buckets + sentinels
    int*   gcur  = (int*)alloc(256 * 4);
    f16*   wtin  = (f16*)alloc(128 * 128 * 2);
    f16*   wtmid = (f16*)alloc(128 * 128 * 2);
    f16*   H16   = (f16*)alloc((size_t)N_NODES * F * 2);   // gemm out (dinv-scaled) / agg in
    f16*   AB16  = (f16*)alloc((size_t)N_NODES * F * 2);   // agg out chain
    // stage aliased into H16 (consumed by binB before gemm1 writes H16):
    // NCBK * BUFCAP * 8 B = 16.06 MB <= 25.6 MB
    int2* stage = (int2*)H16;
    float* sbuf = (float*)AB16;  // aliased: consumed by gemm3 before agg_dot writes

    dim3 b256(256);
    int gN = (N_NODES + 255) / 256;
    int gW = (N_NODES + 15) / 16;
    int gG = (N_NODES + 127) / 128;
    int gA = (N_EDGES + CHUNK - 1) / CHUNK;   // 391

    hipLaunchKernelGGL(k_zero0, dim3(1), b256, 0, stream, gcur, edges);
    hipLaunchKernelGGL(k_binA, dim3(gA), b256, 0, stream, ei, ew, gcur, stage, N_EDGES);
    hipLaunchKernelGGL(k_binB, dim3(NCBK), b256, 0, stream, stage, gcur, edges, row2, dinv);
    hipLaunchKernelGGL(k_wt2, dim3(2), b256, 0, stream, Win, Wmid, wtin, wtmid);

    hipLaunchKernelGGL(k_gemmf, dim3(gG), b256, 0, stream, x, wtin, dinv, H16, N_NODES);
    hipLaunchKernelGGL(k_agg, dim3(gW), b256, 0, stream, H16, row2, edges, dinv, bin, AB16, N_NODES);
    hipLaunchKernelGGL(k_gemm16, dim3(gG), b256, 0, stream, AB16, wtmid, dinv, H16, N_NODES);
    hipLaunchKernelGGL(k_agg, dim3(gW), b256, 0, stream, H16, row2, edges, dinv, bmid, AB16, N_NODES);
    hipLaunchKernelGGL(k_gemm16, dim3(gG), b256, 0, stream, AB16, wtmid, dinv, H16, N_NODES);
    hipLaunchKernelGGL(k_agg_dot, dim3(gW), b256, 0, stream, H16, row2, edges, dinv, bmid, Wfin, sbuf, N_NODES);
    hipLaunchKernelGGL(k_aggs, dim3(gN), b256, 0, stream, sbuf, row2, edges, dinv, bfin, out, N_NODES);
}

// Round 5
// 377.167 us; speedup vs baseline: 1.2807x; 1.0273x over previous
//
#include <hip/hip_runtime.h>
#include <stdint.h>

#define N_NODES 100000
#define N_EDGES 1600000
#define F 128
#define CBN 512                    // nodes per coarse bucket
#define NCBK 196                   // ceil(N_NODES/CBN)
#define CHUNK 4096                 // edges per binA block
#define BUFCAP 10240               // per-bucket region cap (mean 8163 + ~23 sigma)

typedef _Float16 f16;
typedef _Float16 f16x4 __attribute__((ext_vector_type(4)));
typedef _Float16 f16x8 __attribute__((ext_vector_type(8)));
typedef float f32x4 __attribute__((ext_vector_type(4)));

// edge pack: (src << 15) | (fp16 bits of w, sign bit dropped — w in [0,1))
__device__ inline float unpackw(unsigned int p) {
    unsigned short b = (unsigned short)(p & 0x7FFF);
    return (float)__builtin_bit_cast(f16, b);
}

// ---------------- R18 front-end: padded-bucket, no histogram/scan ----------------
// Each bucket cb owns stage[cb*BUFCAP ..] and edges[cb*BUFCAP ..]; binA appends
// via gcur (zero-based), binB compacts within the bucket. CSR is per-node
// (beg,end) pairs (row2) so the inter-bucket padding gaps are harmless.

// ---------------- LDS write-combining binner (R13, proven) ----------------
// Measured R9-R12: scattered/temporally-sparse partial-line writes cost ~5x
// write amplification. binA converts per-edge scatter into per-(block,bin)
// contiguous runs claimed with one atomic each.

__launch_bounds__(256)
__global__ void k_binA(const int* __restrict__ ei, const float* __restrict__ w,
                       int* __restrict__ gcur, int2* __restrict__ stage, int e) {
    __shared__ int hist[256];
    __shared__ int bst[257];
    __shared__ int gb[256];
    __shared__ int ls[256];
    __shared__ int rec[CHUNK];
    __shared__ int meta[CHUNK];
    int tid = threadIdx.x;
    int base = blockIdx.x * CHUNK;
    int cnt = min(CHUNK, e - base);
    hist[tid] = 0;
    __syncthreads();

    int ew_[16], mr_[16];
    int nloc = 0;
    if (cnt == CHUNK) {
#pragma unroll
        for (int k = 0; k < 16; k++) {
            int i = base + tid + k * 256;
            int s = ei[i];
            int d = ei[N_EDGES + i];
            f16 hw = (f16)w[i];
            unsigned short wb = __builtin_bit_cast(unsigned short, hw);
            ew_[k] = (int)(((unsigned int)s << 15) | (wb & 0x7FFF));
            int cb = d >> 9;
            int local = d & (CBN - 1);
            int r = atomicAdd(&hist[cb], 1);
            mr_[k] = (cb << 22) | (local << 13) | r;   // cb:8 local:9 r:13
        }
        nloc = 16;
    } else {
        for (int i = tid; i < cnt; i += 256) {
            int s = ei[base + i];
            int d = ei[N_EDGES + base + i];
            f16 hw = (f16)w[base + i];
            unsigned short wb = __builtin_bit_cast(unsigned short, hw);
            ew_[nloc] = (int)(((unsigned int)s << 15) | (wb & 0x7FFF));
            int cb = d >> 9;
            int local = d & (CBN - 1);
            int r = atomicAdd(&hist[cb], 1);
            mr_[nloc] = (cb << 22) | (local << 13) | r;
            nloc++;
        }
    }
    __syncthreads();
    int v = hist[tid];
    ls[tid] = v;
    __syncthreads();
    for (int off = 1; off < 256; off <<= 1) {
        int t = (tid >= off) ? ls[tid - off] : 0;
        __syncthreads();
        ls[tid] += t;
        __syncthreads();
    }
    bst[tid] = ls[tid] - v;
    if (tid == 255) bst[256] = ls[255];
    __syncthreads();
    for (int k = 0; k < nloc; k++) {
        int m = mr_[k];
        int cb = m >> 22;
        int pos = bst[cb] + (m & 0x1FFF);
        rec[pos] = ew_[k];
        meta[pos] = (cb << 9) | ((m >> 13) & 0x1FF);
    }
    __syncthreads();
    if (tid < NCBK) {
        int c = bst[tid + 1] - bst[tid];
        gb[tid] = c ? atomicAdd(&gcur[tid], c) : 0;
    }
    __syncthreads();
    for (int j = tid; j < cnt; j += 256) {
        int m = meta[j];
        int cb = m >> 9;
        stage[(size_t)cb * BUFCAP + gb[cb] + (j - bst[cb])] = make_int2(m & 511, rec[j]);
    }
}

// binB: one block per coarse bucket. pass1 count locals -> LDS scan -> row2
// write; pass2 permute to CSR order in LDS; coalesced final write + fused dinv.
__launch_bounds__(256)
__global__ void k_binB(const int2* __restrict__ stage, const int* __restrict__ gcur,
                       unsigned int* __restrict__ edges, int2* __restrict__ row2,
                       float* __restrict__ dinv) {
    __shared__ int cnt[CBN];
    __shared__ int ex[CBN + 1];
    __shared__ int cur[CBN];
    __shared__ int ls[256];
    __shared__ unsigned int buf[BUFCAP];
    int tid = threadIdx.x;
    int cb = blockIdx.x;
    int n0 = cb * CBN;
    int nn = min(CBN, N_NODES - n0);
    size_t sbase = (size_t)cb * BUFCAP;
    int ecnt = gcur[cb];
    cnt[tid] = 0;
    cnt[tid + 256] = 0;
    __syncthreads();
    // pass 1: local histogram
    for (int j = tid; j < ecnt; j += 256)
        atomicAdd(&cnt[stage[sbase + j].x], 1);
    __syncthreads();
    // exclusive scan of 512 (2 per thread)
    int a = cnt[2 * tid], b = cnt[2 * tid + 1];
    int s = a + b;
    ls[tid] = s;
    __syncthreads();
    for (int off = 1; off < 256; off <<= 1) {
        int t = (tid >= off) ? ls[tid - off] : 0;
        __syncthreads();
        ls[tid] += t;
        __syncthreads();
    }
    int bx = ls[tid] - s;
    ex[2 * tid] = bx;
    ex[2 * tid + 1] = bx + a;
    cur[2 * tid] = bx;
    cur[2 * tid + 1] = bx + a;
    if (tid == 255) ex[512] = ls[255];
    __syncthreads();
    // per-node (beg,end) pairs — padding gaps between buckets are harmless
    for (int l = tid; l < nn; l += 256)
        row2[n0 + l] = make_int2((int)sbase + ex[l], (int)sbase + ex[l + 1]);
    // pass 2: permute to CSR order in LDS
    for (int j = tid; j < ecnt; j += 256) {
        int2 r = stage[sbase + j];
        int p = atomicAdd(&cur[r.x], 1);
        buf[p] = (unsigned int)r.y;
    }
    __syncthreads();
    for (int j = tid; j < ecnt; j += 256)
        edges[sbase + j] = buf[j];
    // fused dinv: deg = 1 + sum w over the node's CSR slice (in LDS)
    for (int l = tid; l < nn; l += 256) {
        int lo = ex[l];
        int h2 = ex[l + 1];
        float sm = 1.0f;
        for (int j = lo; j < h2; j++) sm += unpackw(buf[j]);
        dinv[n0 + l] = rsqrtf(sm);
    }
}

// ---------------- weight transpose + front-end init (fused) ----------------

__global__ void k_wt2(const float* __restrict__ Wa, const float* __restrict__ Wb,
                      f16* __restrict__ Wta, f16* __restrict__ Wtb,
                      int* __restrict__ gcur, unsigned int* __restrict__ edges) {
    int t = threadIdx.x;
    if (blockIdx.x == 2) {
        if (t < NCBK) gcur[t] = 0;
        // 8 zero sentinels past the last bucket region (uint4 tail overread)
        if (t >= 248) edges[(size_t)NCBK * BUFCAP + (t - 248)] = 0u;
        return;
    }
    const float* W = blockIdx.x ? Wb : Wa;
    f16* Wt = blockIdx.x ? Wtb : Wta;
#pragma unroll
    for (int it = 0; it < 64; it++) {
        int idx = t + it * 256;
        int k = idx >> 7, n = idx & 127;
        Wt[n * 128 + k] = (f16)W[idx];
    }
}

// ---------------- fp16 MFMA GEMM (layer 1, fused fp32->fp16 A conversion) ----------------

#define LDK 136

__launch_bounds__(256, 2)
__global__ void k_gemmf(const float* __restrict__ A, const f16* __restrict__ Wt,
                        const float* __restrict__ dinv, f16* __restrict__ H, int nrows) {
    __shared__ f16 Ws[128 * LDK];
    int tid = threadIdx.x;
    int r0 = blockIdx.x * 128;
    int wave = tid >> 6;
    int lane = tid & 63;
    int lrow = lane & 15;
    int quad = lane >> 4;

    f16x8 a[2][4];
#pragma unroll
    for (int mt = 0; mt < 2; mt++) {
        int row = r0 + wave * 32 + mt * 16 + lrow;
#pragma unroll
        for (int kc = 0; kc < 4; kc++) {
            if (row < nrows) {
                float4 lo = *(const float4*)&A[(size_t)row * F + kc * 32 + quad * 8];
                float4 hi = *(const float4*)&A[(size_t)row * F + kc * 32 + quad * 8 + 4];
                f16x8 f;
                f[0] = (f16)lo.x; f[1] = (f16)lo.y; f[2] = (f16)lo.z; f[3] = (f16)lo.w;
                f[4] = (f16)hi.x; f[5] = (f16)hi.y; f[6] = (f16)hi.z; f[7] = (f16)hi.w;
                a[mt][kc] = f;
            } else {
                a[mt][kc] = (f16x8){};
            }
        }
    }
#pragma unroll
    for (int it = 0; it < 8; it++) {
        int c = tid + it * 256;
        int rw = c >> 4;
        int off = (c & 15) * 8;
        *(f16x8*)&Ws[rw * LDK + off] = *(const f16x8*)&Wt[rw * 128 + off];
    }
    __syncthreads();

    f32x4 acc[2][8] = {};
#pragma unroll
    for (int kc = 0; kc < 4; kc++) {
        f16x8 b[8];
#pragma unroll
        for (int nt = 0; nt < 8; nt++)
            b[nt] = *(const f16x8*)&Ws[(nt * 16 + lrow) * LDK + kc * 32 + quad * 8];
#pragma unroll
        for (int nt = 0; nt < 8; nt++) {
            acc[0][nt] = __builtin_amdgcn_mfma_f32_16x16x32_f16(a[0][kc], b[nt], acc[0][nt], 0, 0, 0);
            acc[1][nt] = __builtin_amdgcn_mfma_f32_16x16x32_f16(a[1][kc], b[nt], acc[1][nt], 0, 0, 0);
        }
    }
    __syncthreads();
#pragma unroll
    for (int mt = 0; mt < 2; mt++) {
#pragma unroll
        for (int r = 0; r < 4; r++) {
            int lr = wave * 32 + mt * 16 + quad * 4 + r;
            int grow = r0 + lr;
            float dv = (grow < nrows) ? dinv[grow] : 0.f;
#pragma unroll
            for (int nt = 0; nt < 8; nt++)
                Ws[lr * 132 + nt * 16 + lrow] = (f16)(acc[mt][nt][r] * dv);
        }
    }
    __syncthreads();
#pragma unroll
    for (int it = 0; it < 8; it++) {
        int c = it * 256 + tid;
        int rw = c >> 4;
        int col = (c & 15) * 8;
        int grow = r0 + rw;
        if (grow < nrows)
            *(f16x8*)&H[(size_t)grow * F + col] = *(const f16x8*)&Ws[rw * 132 + col];
    }
}

// ---------------- R19: fused aggregation + GEMM ----------------
// One block = 128 nodes. Phase 1: R16 quarter-wave gather per node, relu'd
// rows written to a 34 KB LDS tile (the GEMM A-tile) instead of global AB16 —
// kills the 25.6 MB write + 25.6 MB read round-trip per layer. Phase 2: a-frags
// to registers; the SAME LDS buffer is then re-staged with Wt (keeps LDS at
// 34 KB -> 4 blocks/CU, preserving gather-phase occupancy); MFMA; dinv
// epilogue; coalesced store. Hin/Hout ping-pong (gather reads any row of Hin
// while other blocks write Hout).
__launch_bounds__(256, 4)
__global__ void k_agg_gemm(const f16* __restrict__ Hin, const int2* __restrict__ row2,
                           const unsigned int* __restrict__ edges,
                           const float* __restrict__ dinv, const float* __restrict__ bias,
                           const f16* __restrict__ Wt, f16* __restrict__ Hout, int nrows) {
    __shared__ f16 S[128 * LDK];   // phase1: A-tile; then Ws; then epilogue buffer
    int tid = threadIdx.x;
    int r0 = blockIdx.x * 128;
    int wave = tid >> 6;
    int lane = tid & 63;
    int sub = lane & 15;
    int quad = lane >> 4;

    // ---- phase 1: aggregate this block's 128 nodes into S ----
    float4 b0 = *(const float4*)&bias[sub * 8];
    float4 b1 = *(const float4*)&bias[sub * 8 + 4];
    float bb[8] = {b0.x, b0.y, b0.z, b0.w, b1.x, b1.y, b1.z, b1.w};
    for (int it = 0; it < 8; it++) {
        int l = wave * 32 + it * 4 + quad;     // local row 0..127
        int node = r0 + l;
        f16x8 o = (f16x8){};
        if (node < nrows) {
            int2 rr = row2[node];
            int beg = rr.x, end = rr.y;
            float acc0[8] = {}, acc1[8] = {}, acc2[8] = {}, acc3[8] = {};
            for (int t = (beg & ~3); t < end; t += 8) {
                uint4 ea = *(const uint4*)&edges[t];
                uint4 eb = *(const uint4*)&edges[t + 4];
                unsigned int e[8] = {ea.x, ea.y, ea.z, ea.w, eb.x, eb.y, eb.z, eb.w};
                float w[8];
                unsigned int srcw[8];
#pragma unroll
                for (int k = 0; k < 8; k++) {
                    bool live = (t + k >= beg) && (t + k < end);
                    w[k] = live ? unpackw(e[k]) : 0.f;
                    srcw[k] = (t + k < end) ? e[k] : ea.x;
                }
                f16x8 v[8];
#pragma unroll
                for (int k = 0; k < 8; k++)
                    v[k] = *(const f16x8*)&Hin[(size_t)(srcw[k] >> 15) * F + sub * 8];
#pragma unroll
                for (int j = 0; j < 8; j++) {
                    acc0[j] = fmaf(w[0], (float)v[0][j], acc0[j]);
                    acc1[j] = fmaf(w[1], (float)v[1][j], acc1[j]);
                    acc2[j] = fmaf(w[2], (float)v[2][j], acc2[j]);
                    acc3[j] = fmaf(w[3], (float)v[3][j], acc3[j]);
                    acc0[j] = fmaf(w[4], (float)v[4][j], acc0[j]);
                    acc1[j] = fmaf(w[5], (float)v[5][j], acc1[j]);
                    acc2[j] = fmaf(w[6], (float)v[6][j], acc2[j]);
                    acc3[j] = fmaf(w[7], (float)v[7][j], acc3[j]);
                }
            }
            float dd = dinv[node];
            f16x8 h = *(const f16x8*)&Hin[(size_t)node * F + sub * 8];
#pragma unroll
            for (int j = 0; j < 8; j++) {
                float a = acc0[j] + acc1[j] + acc2[j] + acc3[j] + (float)h[j];
                o[j] = (f16)fmaxf(fmaf(dd, a, bb[j]), 0.f);
            }
        }
        *(f16x8*)&S[l * LDK + sub * 8] = o;
    }
    __syncthreads();

    // ---- phase 2: a-frags from S (rows stride LDK: 2-way bank alias, free) ----
    f16x8 a[2][4];
#pragma unroll
    for (int mt = 0; mt < 2; mt++) {
        int l = wave * 32 + mt * 16 + sub;
#pragma unroll
        for (int kc = 0; kc < 4; kc++)
            a[mt][kc] = *(const f16x8*)&S[l * LDK + kc * 32 + quad * 8];
    }
    __syncthreads();
    // ---- re-stage S with Wt ----
#pragma unroll
    for (int it = 0; it < 8; it++) {
        int c = tid + it * 256;
        int rw = c >> 4;
        int off = (c & 15) * 8;
        *(f16x8*)&S[rw * LDK + off] = *(const f16x8*)&Wt[rw * 128 + off];
    }
    __syncthreads();

    f32x4 acc[2][8] = {};
#pragma unroll
    for (int kc = 0; kc < 4; kc++) {
        f16x8 b[8];
#pragma unroll
        for (int nt = 0; nt < 8; nt++)
            b[nt] = *(const f16x8*)&S[(nt * 16 + sub) * LDK + kc * 32 + quad * 8];
#pragma unroll
        for (int nt = 0; nt < 8; nt++) {
            acc[0][nt] = __builtin_amdgcn_mfma_f32_16x16x32_f16(a[0][kc], b[nt], acc[0][nt], 0, 0, 0);
            acc[1][nt] = __builtin_amdgcn_mfma_f32_16x16x32_f16(a[1][kc], b[nt], acc[1][nt], 0, 0, 0);
        }
    }
    __syncthreads();
#pragma unroll
    for (int mt = 0; mt < 2; mt++) {
#pragma unroll
        for (int r = 0; r < 4; r++) {
            int lr = wave * 32 + mt * 16 + quad * 4 + r;
            int grow = r0 + lr;
            float dv = (grow < nrows) ? dinv[grow] : 0.f;
#pragma unroll
            for (int nt = 0; nt < 8; nt++)
                S[lr * 132 + nt * 16 + sub] = (f16)(acc[mt][nt][r] * dv);
        }
    }
    __syncthreads();
#pragma unroll
    for (int it = 0; it < 8; it++) {
        int c = it * 256 + tid;
        int rw = c >> 4;
        int col = (c & 15) * 8;
        int grow = r0 + rw;
        if (grow < nrows)
            *(f16x8*)&Hout[(size_t)grow * F + col] = *(const f16x8*)&S[rw * 132 + col];
    }
}

// agg3 fused with final dot: s'[node] = dinv[node] * ( relu(agg3) . Wfin )
__launch_bounds__(256)
__global__ void k_agg_dot(const f16* __restrict__ H16, const int2* __restrict__ row2,
                          const unsigned int* __restrict__ edges,
                          const float* __restrict__ dinv, const float* __restrict__ bias,
                          const float* __restrict__ Wf, float* __restrict__ sout, int n) {
    int node = blockIdx.x * 16 + (threadIdx.x >> 4);
    if (node >= n) return;
    int sub = threadIdx.x & 15;
    int2 rr = row2[node];
    int beg = rr.x, end = rr.y;
    float acc0[8] = {}, acc1[8] = {}, acc2[8] = {}, acc3[8] = {};
    for (int t = (beg & ~3); t < end; t += 8) {
        uint4 ea = *(const uint4*)&edges[t];
        uint4 eb = *(const uint4*)&edges[t + 4];
        unsigned int e[8] = {ea.x, ea.y, ea.z, ea.w, eb.x, eb.y, eb.z, eb.w};
        float w[8];
        unsigned int srcw[8];
#pragma unroll
        for (int k = 0; k < 8; k++) {
            bool live = (t + k >= beg) && (t + k < end);
            w[k] = live ? unpackw(e[k]) : 0.f;
            srcw[k] = (t + k < end) ? e[k] : ea.x;
        }
        f16x8 v[8];
#pragma unroll
        for (int k = 0; k < 8; k++)
            v[k] = *(const f16x8*)&H16[(size_t)(srcw[k] >> 15) * F + sub * 8];
#pragma unroll
        for (int j = 0; j < 8; j++) {
            acc0[j] = fmaf(w[0], (float)v[0][j], acc0[j]);
            acc1[j] = fmaf(w[1], (float)v[1][j], acc1[j]);
            acc2[j] = fmaf(w[2], (float)v[2][j], acc2[j]);
            acc3[j] = fmaf(w[3], (float)v[3][j], acc3[j]);
            acc0[j] = fmaf(w[4], (float)v[4][j], acc0[j]);
            acc1[j] = fmaf(w[5], (float)v[5][j], acc1[j]);
            acc2[j] = fmaf(w[6], (float)v[6][j], acc2[j]);
            acc3[j] = fmaf(w[7], (float)v[7][j], acc3[j]);
        }
    }
    float dd = dinv[node];
    f16x8 h = *(const f16x8*)&H16[(size_t)node * F + sub * 8];
    float4 b0 = *(const float4*)&bias[sub * 8];
    float4 b1 = *(const float4*)&bias[sub * 8 + 4];
    float bb[8] = {b0.x, b0.y, b0.z, b0.w, b1.x, b1.y, b1.z, b1.w};
    float4 w0v = *(const float4*)&Wf[sub * 8];
    float4 w1v = *(const float4*)&Wf[sub * 8 + 4];
    float ww[8] = {w0v.x, w0v.y, w0v.z, w0v.w, w1v.x, w1v.y, w1v.z, w1v.w};
    float p = 0.f;
#pragma unroll
    for (int j = 0; j < 8; j++) {
        float a = acc0[j] + acc1[j] + acc2[j] + acc3[j] + (float)h[j];
        p += fmaxf(fmaf(dd, a, bb[j]), 0.f) * ww[j];
    }
    p += __shfl_xor(p, 8, 64);
    p += __shfl_xor(p, 4, 64);
    p += __shfl_xor(p, 2, 64);
    p += __shfl_xor(p, 1, 64);
    if (sub == 0) sout[node] = dd * p;
}

__global__ void k_aggs(const float* __restrict__ s, const int2* __restrict__ row2,
                       const unsigned int* __restrict__ edges,
                       const float* __restrict__ dinv, const float* __restrict__ bf,
                       float* __restrict__ out, int n) {
    int i = blockIdx.x * blockDim.x + threadIdx.x;
    if (i >= n) return;
    float dd = dinv[i];
    float ae = s[i];
    int2 rr = row2[i];
    for (int j = rr.x; j < rr.y; j++) {
        unsigned int p = edges[j];
        ae = fmaf(unpackw(p), s[p >> 15], ae);
    }
    out[i] = fmaf(dd, ae, bf[0]);
}

// ---------------- host launch ----------------

extern "C" void kernel_launch(void* const* d_in, const int* in_sizes, int n_in,
                              void* d_out, int out_size, void* d_ws, size_t ws_size,
                              hipStream_t stream) {
    const float* x    = (const float*)d_in[0];
    const int*   ei   = (const int*)d_in[1];
    const float* ew   = (const float*)d_in[2];
    const float* Win  = (const float*)d_in[3];
    const float* bin  = (const float*)d_in[4];
    const float* Wmid = (const float*)d_in[5];
    const float* bmid = (const float*)d_in[6];
    const float* Wfin = (const float*)d_in[7];
    const float* bfin = (const float*)d_in[8];
    float* out = (float*)d_out;

    char* ws = (char*)d_ws;
    size_t off = 0;
    auto alloc = [&](size_t bytes) -> char* {
        char* p = ws + off;
        off = (off + bytes + 255) & ~(size_t)255;
        return p;
    };
    float* dinv  = (float*)alloc((size_t)N_NODES * 4);
    int2*  row2  = (int2*)alloc((size_t)N_NODES * 8);
    unsigned int* edges = (unsigned int*)alloc(((size_t)NCBK * BUFCAP + 8) * 4);  // padded buckets + sentinels
    int*   gcur  = (int*)alloc(256 * 4);
    f16*   wtin  = (f16*)alloc(128 * 128 * 2);
    f16*   wtmid = (f16*)alloc(128 * 128 * 2);
    f16*   Ha    = (f16*)alloc((size_t)N_NODES * F * 2);   // ping
    f16*   Hb    = (f16*)alloc((size_t)N_NODES * F * 2);   // pong
    // stage aliased into Ha (consumed by binB before gemmf writes Ha):
    // NCBK * BUFCAP * 8 B = 16.06 MB <= 25.6 MB
    int2* stage = (int2*)Ha;
    float* sbuf = (float*)Hb;  // aliased: Hb consumed by fused2 before agg_dot writes

    dim3 b256(256);
    int gN = (N_NODES + 255) / 256;
    int gW = (N_NODES + 15) / 16;
    int gG = (N_NODES + 127) / 128;
    int gA = (N_EDGES + CHUNK - 1) / CHUNK;   // 391

    hipLaunchKernelGGL(k_wt2, dim3(3), b256, 0, stream, Win, Wmid, wtin, wtmid, gcur, edges);
    hipLaunchKernelGGL(k_binA, dim3(gA), b256, 0, stream, ei, ew, gcur, stage, N_EDGES);
    hipLaunchKernelGGL(k_binB, dim3(NCBK), b256, 0, stream, stage, gcur, edges, row2, dinv);

    hipLaunchKernelGGL(k_gemmf, dim3(gG), b256, 0, stream, x, wtin, dinv, Ha, N_NODES);
    hipLaunchKernelGGL(k_agg_gemm, dim3(gG), b256, 0, stream, Ha, row2, edges, dinv, bin, wtmid, Hb, N_NODES);
    hipLaunchKernelGGL(k_agg_gemm, dim3(gG), b256, 0, stream, Hb, row2, edges, dinv, bmid, wtmid, Ha, N_NODES);
    hipLaunchKernelGGL(k_agg_dot, dim3(gW), b256, 0, stream, Ha, row2, edges, dinv, bmid, Wfin, sbuf, N_NODES);
    hipLaunchKernelGGL(k_aggs, dim3(gN), b256, 0, stream, sbuf, row2, edges, dinv, bfin, out, N_NODES);
}